// Round 11
// baseline (92.731 us; speedup 1.0000x reference)
//
#include <hip/hip_runtime.h>

#define BN_EPS 1e-5f
#define SR_STEP  16384      // per (t,kc): 256 o * 64B
#define BQ_KC    13088      // 6 rows * 34 slots * 64B + 32B pad (bank rotate)
#define KSCALE   (0.7f / 8388608.0f)

typedef __attribute__((ext_vector_type(4))) int int32x4;

// ---------------------------------------------------------------------------
// Weight prep (both layers, one launch): grid 512; set = blockIdx.x>>8.
// alpha[o] = mean|w[o]| ; Sr[(t*4+kc)*256 + o][64] = sign i8.
// ---------------------------------------------------------------------------
__global__ void prep_w_kernel(const float* __restrict__ w1,
                              signed char* __restrict__ Sr1,
                              float* __restrict__ alpha1,
                              const float* __restrict__ w2,
                              signed char* __restrict__ Sr2,
                              float* __restrict__ alpha2) {
    int set = blockIdx.x >> 8;
    const float* w = set ? w2 : w1;
    signed char* Sr = set ? Sr2 : Sr1;
    float* alpha = set ? alpha2 : alpha1;
    int o = blockIdx.x & 255;
    int c = threadIdx.x;  // 256
    const float* wp = w + (o * 256 + c) * 9;
    float s = 0.f;
    __shared__ __align__(16) signed char lsg[9][256];
    __shared__ float red[256];
#pragma unroll
    for (int j = 0; j < 9; ++j) {
        float v = wp[j];
        s += fabsf(v);
        lsg[j][c] = v > 0.f ? 1 : (v < 0.f ? -1 : 0);
    }
    red[c] = s;
    __syncthreads();
    for (int off = 128; off > 0; off >>= 1) {
        if (c < off) red[c] += red[c + off];
        __syncthreads();
    }
    if (c == 0) alpha[o] = red[0] / 2304.0f;
    if (c < 144) {
        int t = c / 16, u = c % 16;
        int c0 = u * 16;
        int kc = c0 >> 6, cb = c0 & 63;
        int32x4 v = *(const int32x4*)(&lsg[t][c0]);
        *(int32x4*)(Sr + (size_t)((t * 4 + kc) * 256 + o) * 64 + cb) = v;
    }
}

// ---------------------------------------------------------------------------
// partials[bid] = block-sum of |bn1(x)| (deterministic tree).
// ---------------------------------------------------------------------------
__global__ void bnabs_reduce_kernel(const float* __restrict__ x,
                                    const float* __restrict__ gamma,
                                    const float* __restrict__ beta,
                                    const float* __restrict__ mean,
                                    const float* __restrict__ var,
                                    float* __restrict__ partials) {
    int tid = blockIdx.x * blockDim.x + threadIdx.x;
    int nthreads = gridDim.x * blockDim.x;
    const float4* x4 = (const float4*)x;
    float s = 0.f;
    for (int i = tid; i < 2097152; i += nthreads) {
        int c = (i >> 8) & 255;
        float inv = gamma[c] * rsqrtf(var[c] + BN_EPS);
        float b = beta[c] - mean[c] * inv;
        float4 v = x4[i];
        s += fabsf(v.x * inv + b) + fabsf(v.y * inv + b) +
             fabsf(v.z * inv + b) + fabsf(v.w * inv + b);
    }
    __shared__ float red[256];
    red[threadIdx.x] = s;
    __syncthreads();
    for (int off = 128; off > 0; off >>= 1) {
        if (threadIdx.x < off) red[threadIdx.x] += red[threadIdx.x + off];
        __syncthreads();
    }
    if (threadIdx.x == 0) partials[blockIdx.x] = red[0];
}

// ---------------------------------------------------------------------------
// Fused TBN conv: in-block quantization into LDS (conflict-free writes),
// then i8 MFMA 16x16x64 over 36 (kc,t) steps, barrier-free main loop with
// a 4-deep A-register ring (exact counted vmcnt).
// 512 blocks x 4 waves (2x2); block 128o x 128px, wave 64o x 64px.
// ---------------------------------------------------------------------------
template <bool FUSE>
__global__ __launch_bounds__(256, 2) void tbn_conv_kernel(
    const float* __restrict__ src,        // quant source AND residual (NCHW)
    const signed char* __restrict__ Sr,   // [t*4+kc][256][64] i8
    const float* __restrict__ alpha,      // [256]
    float* __restrict__ out,              // [32][256][1024] f32
    const float* __restrict__ dpart, int nPart,  // delta partials
    const float* __restrict__ qg, const float* __restrict__ qb,
    const float* __restrict__ qm, const float* __restrict__ qv,   // own BN
    const float* __restrict__ fg, const float* __restrict__ fbt,
    const float* __restrict__ fm, const float* __restrict__ fv,   // next BN
    float* __restrict__ partials) {
    __shared__ __align__(16) signed char Bq[4 * BQ_KC];  // 52352 B
    __shared__ float sInv[256], sB[256];
    __shared__ float sAl[128], sInvS[128], sBS[128];
    __shared__ float red[256];

    int bid = blockIdx.x;
    int wg = (bid & 7) * 64 + (bid >> 3);  // bijective, 512 % 8 == 0
    int n = wg >> 4;
    int pb = (wg >> 1) & 7;
    int ob = wg & 1;
    int tid = threadIdx.x, lane = tid & 63, wid = tid >> 6;
    int l15 = lane & 15, kg = lane >> 4;
    int wr = wid >> 1, wc = wid & 1;
    int y0 = pb * 4;

    // ---- prologue A: BN params + delta partial sums ----
    {
        float inv = qg[tid] * rsqrtf(qv[tid] + BN_EPS);
        sInv[tid] = inv;
        sB[tid] = qb[tid] - qm[tid] * inv;
    }
    if (tid < 128) {
        int o = ob * 128 + tid;
        sAl[tid] = alpha[o];
        if (FUSE) {
            float inv = fg[o] * rsqrtf(fv[o] + BN_EPS);
            sInvS[tid] = inv;
            sBS[tid] = fbt[o] - fm[o] * inv;
        }
    }
    float s = 0.f;
    for (int i = tid; i < nPart; i += 256) s += dpart[i];
    red[tid] = s;
    __syncthreads();
    for (int off = 128; off > 0; off >>= 1) {
        if (tid < off) red[tid] += red[tid + off];
        __syncthreads();
    }
    float delta = red[0] * KSCALE;

    // ---- prologue B: quantize 6x34x256 window into Bq ----
    // piece mapping: cg = idx&15 (concurrent lanes span kc/kgp -> 2-way banks),
    // quad = (idx>>4)&7, row = idx>>7. piece = 4 px x 16 ch.
    const float4* src4 = (const float4*)src + (size_t)n * 65536;
#pragma unroll
    for (int k = 0; k < 3; ++k) {
        int idx = tid + 256 * k;
        int cg = idx & 15;           // 16-channel group
        int quad = (idx >> 4) & 7;   // 4-px group within row
        int row = idx >> 7;          // 0..5 (padded window row)
        int absrow = y0 + row - 1;
        int wrd[4][4];
#pragma unroll
        for (int px = 0; px < 4; ++px)
#pragma unroll
            for (int d = 0; d < 4; ++d) wrd[px][d] = 0;
        if (absrow >= 0 && absrow < 32) {
#pragma unroll
            for (int j = 0; j < 16; ++j) {
                int c = cg * 16 + j;
                float4 v = src4[(size_t)c * 256 + absrow * 8 + quad];
                float inv = sInv[c], bb = sB[c];
                float va[4] = {v.x, v.y, v.z, v.w};
#pragma unroll
                for (int px = 0; px < 4; ++px) {
                    float t = va[px] * inv + bb;
                    int q = t > delta ? 1 : (t < -delta ? -1 : 0);
                    wrd[px][j >> 2] |= (q & 255) << (8 * (j & 3));
                }
            }
        }
        int kc = cg >> 2, kgp = cg & 3;
#pragma unroll
        for (int px = 0; px < 4; ++px) {
            int slot = quad * 4 + px + 1;
            int dst = kc * BQ_KC + row * 2176 + slot * 64 +
                      (((kgp + (slot >> 1)) & 3) << 4);
            int32x4 vv;
            vv[0] = wrd[px][0]; vv[1] = wrd[px][1];
            vv[2] = wrd[px][2]; vv[3] = wrd[px][3];
            *(int32x4*)(&Bq[dst]) = vv;
        }
    }
    // halo columns (slot 0 and 33): 192 zero pieces
    if (tid < 192) {
        int cg = tid & 15;
        int rest = tid >> 4;         // 0..11
        int row = rest >> 1, side = rest & 1;
        int slot = side ? 33 : 0;
        int kc = cg >> 2, kgp = cg & 3;
        int dst = kc * BQ_KC + row * 2176 + slot * 64 +
                  (((kgp + (slot >> 1)) & 3) << 4);
        int32x4 z; z[0] = 0; z[1] = 0; z[2] = 0; z[3] = 0;
        *(int32x4*)(&Bq[dst]) = z;
    }
    __syncthreads();   // drains x loads + Bq writes; Bq read-only hereafter

    // ---- main loop: barrier-free, 4-deep A ring only in vmcnt FIFO ----
    int o0 = ob * 128 + wr * 64;
    const signed char* Abase = Sr + (size_t)(o0 + l15) * 64 + kg * 16;

    int32x4 acc[4][4];
#pragma unroll
    for (int m = 0; m < 4; ++m)
#pragma unroll
        for (int nn = 0; nn < 4; ++nn) {
            acc[m][nn][0] = 0; acc[m][nn][1] = 0;
            acc[m][nn][2] = 0; acc[m][nn][3] = 0;
        }

    int32x4 fa[4][4], fb[2][4];

#define GLD(D, P) \
    asm volatile("global_load_dwordx4 %0, %1, off" : "=v"(D) : "v"(P))
#define SLAB(I) ((((I) % 9) * 4) + ((I) / 9))
#define LOADA(I)                                                              \
    do {                                                                      \
        const signed char* pa_ = Abase + (size_t)SLAB(I) * SR_STEP;           \
        GLD(fa[(I) % 4][0], pa_);                                             \
        GLD(fa[(I) % 4][1], pa_ + 1024);                                      \
        GLD(fa[(I) % 4][2], pa_ + 2048);                                      \
        GLD(fa[(I) % 4][3], pa_ + 3072);                                      \
    } while (0)
#define LOADB(J, BUF)                                                         \
    do {                                                                      \
        const int kcj_ = (J) / 9, tj_ = (J) % 9;                              \
        const int kh_ = tj_ / 3 - 1, kw_ = tj_ % 3 - 1;                       \
        _Pragma("unroll")                                                     \
        for (int nn = 0; nn < 4; ++nn) {                                      \
            const int row_ = wc * 2 + (nn >> 1) + 1 + kh_;                    \
            int slot_ = (nn & 1) * 16 + l15 + 1 + kw_;                        \
            int off_ = kcj_ * BQ_KC + row_ * 2176 + slot_ * 64 +              \
                       (((kg + (slot_ >> 1)) & 3) << 4);                      \
            fb[BUF][nn] = *(const int32x4*)(&Bq[off_]);                       \
        }                                                                     \
    } while (0)
#define MFMA16(I, BUF)                                                        \
    do {                                                                      \
        _Pragma("unroll")                                                     \
        for (int m = 0; m < 4; ++m)                                           \
            _Pragma("unroll")                                                 \
            for (int nn = 0; nn < 4; ++nn)                                    \
                acc[m][nn] = __builtin_amdgcn_mfma_i32_16x16x64_i8(           \
                    fa[(I) % 4][m], fb[BUF][nn], acc[m][nn], 0, 0, 0);        \
    } while (0)
#define WAITV(N)                                                              \
    do { asm volatile("s_waitcnt vmcnt(" #N ")" ::: "memory");                \
         __builtin_amdgcn_sched_barrier(0); } while (0)

    LOADA(0); LOADA(1); LOADA(2); LOADA(3);
    LOADB(0, 0);
    // FIFO-exact: outstanding before wait at step i = A(i..min(i+3,35));
    // retire A(i): N=12 for i<=32, 8 at 33, 4 at 34, 0 at 35.
#pragma unroll
    for (int i = 0; i < 36; ++i) {
        if (i <= 32)      WAITV(12);
        else if (i == 33) WAITV(8);
        else if (i == 34) WAITV(4);
        else              WAITV(0);
        if (i < 35) LOADB(i + 1, (i + 1) & 1);
        MFMA16(i, i & 1);
        if (i + 4 <= 35) LOADA(i + 4);
    }
#undef GLD
#undef SLAB
#undef LOADA
#undef LOADB
#undef MFMA16
#undef WAITV

    // ---- epilogue: D col = l15 (pixel), row = kg*4 + r ----
    float psum = 0.f;
#pragma unroll
    for (int m = 0; m < 4; ++m) {
#pragma unroll
        for (int r = 0; r < 4; ++r) {
            int oLoc = wr * 64 + m * 16 + kg * 4 + r;  // 0..127
            int o = ob * 128 + oLoc;
            float al = sAl[oLoc];
            float inv = 0.f, bb = 0.f;
            if (FUSE) { inv = sInvS[oLoc]; bb = sBS[oLoc]; }
            const float* rp = src + (size_t)n * 262144 + (size_t)o * 1024;
            float* op = out + (size_t)n * 262144 + (size_t)o * 1024;
#pragma unroll
            for (int nn = 0; nn < 4; ++nn) {
                int p = pb * 128 + wc * 64 + nn * 16 + l15;
                float hv = rp[p] + al * (float)acc[m][nn][r];
                op[p] = hv;
                if (FUSE) psum += fabsf(hv * inv + bb);
            }
        }
    }
    if (FUSE) {
        __syncthreads();           // red[] reuse safe-guard
        red[tid] = psum;
        __syncthreads();
        for (int off = 128; off > 0; off >>= 1) {
            if (tid < off) red[tid] += red[tid + off];
            __syncthreads();
        }
        if (tid == 0) partials[wg] = red[0];
    }
}

// ---------------------------------------------------------------------------
extern "C" void kernel_launch(void* const* d_in, const int* in_sizes, int n_in,
                              void* d_out, int out_size, void* d_ws, size_t ws_size,
                              hipStream_t stream) {
    (void)in_sizes; (void)n_in; (void)out_size; (void)ws_size;
    const float* x  = (const float*)d_in[0];
    const float* w1 = (const float*)d_in[1];
    const float* w2 = (const float*)d_in[2];
    const float* g1 = (const float*)d_in[3];
    const float* b1 = (const float*)d_in[4];
    const float* m1 = (const float*)d_in[5];
    const float* v1 = (const float*)d_in[6];
    const float* g2 = (const float*)d_in[7];
    const float* b2 = (const float*)d_in[8];
    const float* m2 = (const float*)d_in[9];
    const float* v2 = (const float*)d_in[10];
    float* out = (float*)d_out;
    char* ws = (char*)d_ws;

    float* red1   = (float*)(ws + 4096);       // 4096 floats
    float* redc   = (float*)(ws + 24576);      // 512 floats
    float* alpha1 = (float*)(ws + 28672);
    float* alpha2 = (float*)(ws + 29696);
    signed char* Sr1 = (signed char*)(ws + ((size_t)1 << 20));
    signed char* Sr2 = (signed char*)(ws + ((size_t)2 << 20));
    float* h         = (float*)(ws + ((size_t)4 << 20));   // 134 MB

    prep_w_kernel<<<512, 256, 0, stream>>>(w1, Sr1, alpha1, w2, Sr2, alpha2);
    bnabs_reduce_kernel<<<4096, 256, 0, stream>>>(x, g1, b1, m1, v1, red1);
    tbn_conv_kernel<true><<<512, 256, 0, stream>>>(
        x, Sr1, alpha1, h, red1, 4096,
        g1, b1, m1, v1, g2, b2, m2, v2, redc);
    tbn_conv_kernel<false><<<512, 256, 0, stream>>>(
        h, Sr2, alpha2, out, redc, 512,
        g2, b2, m2, v2, g2, b2, m2, v2, redc);
}

// Round 13
// 84.452 us; speedup vs baseline: 1.0980x; 1.0980x over previous
//
#include <hip/hip_runtime.h>

#define BN_EPS 1e-5f
#define SR_STEP  16384      // per (t,kc): 256 o * 64B
#define BQ_KC    8704       // 4 rows * 34 slots * 64B per kc
#define KSCALE   (0.7f / 8388608.0f)

typedef __attribute__((ext_vector_type(4))) int int32x4;

// ---------------------------------------------------------------------------
// Weight prep (both layers, one launch): grid 512; set = blockIdx.x>>8.
// alpha[o] = mean|w[o]| ; Sr[(t*4+kc)*256 + o][64] = sign i8.
// ---------------------------------------------------------------------------
__global__ void prep_w_kernel(const float* __restrict__ w1,
                              signed char* __restrict__ Sr1,
                              float* __restrict__ alpha1,
                              const float* __restrict__ w2,
                              signed char* __restrict__ Sr2,
                              float* __restrict__ alpha2) {
    int set = blockIdx.x >> 8;
    const float* w = set ? w2 : w1;
    signed char* Sr = set ? Sr2 : Sr1;
    float* alpha = set ? alpha2 : alpha1;
    int o = blockIdx.x & 255;
    int c = threadIdx.x;  // 256
    const float* wp = w + (o * 256 + c) * 9;
    float s = 0.f;
    __shared__ __align__(16) signed char lsg[9][256];
    __shared__ float red[256];
#pragma unroll
    for (int j = 0; j < 9; ++j) {
        float v = wp[j];
        s += fabsf(v);
        lsg[j][c] = v > 0.f ? 1 : (v < 0.f ? -1 : 0);
    }
    red[c] = s;
    __syncthreads();
    for (int off = 128; off > 0; off >>= 1) {
        if (c < off) red[c] += red[c + off];
        __syncthreads();
    }
    if (c == 0) alpha[o] = red[0] / 2304.0f;
    if (c < 144) {
        int t = c / 16, u = c % 16;
        int c0 = u * 16;
        int kc = c0 >> 6, cb = c0 & 63;
        int32x4 v = *(const int32x4*)(&lsg[t][c0]);
        *(int32x4*)(Sr + (size_t)((t * 4 + kc) * 256 + o) * 64 + cb) = v;
    }
}

// ---------------------------------------------------------------------------
// partials[bid] = block-sum of |bn1(x)| (deterministic tree).
// ---------------------------------------------------------------------------
__global__ void bnabs_reduce_kernel(const float* __restrict__ x,
                                    const float* __restrict__ gamma,
                                    const float* __restrict__ beta,
                                    const float* __restrict__ mean,
                                    const float* __restrict__ var,
                                    float* __restrict__ partials) {
    int tid = blockIdx.x * blockDim.x + threadIdx.x;
    int nthreads = gridDim.x * blockDim.x;
    const float4* x4 = (const float4*)x;
    float s = 0.f;
    for (int i = tid; i < 2097152; i += nthreads) {
        int c = (i >> 8) & 255;
        float inv = gamma[c] * rsqrtf(var[c] + BN_EPS);
        float b = beta[c] - mean[c] * inv;
        float4 v = x4[i];
        s += fabsf(v.x * inv + b) + fabsf(v.y * inv + b) +
             fabsf(v.z * inv + b) + fabsf(v.w * inv + b);
    }
    __shared__ float red[256];
    red[threadIdx.x] = s;
    __syncthreads();
    for (int off = 128; off > 0; off >>= 1) {
        if (threadIdx.x < off) red[threadIdx.x] += red[threadIdx.x + off];
        __syncthreads();
    }
    if (threadIdx.x == 0) partials[blockIdx.x] = red[0];
}

// ---------------------------------------------------------------------------
// Fused TBN conv: in-block quantization into LDS, then i8 MFMA 16x16x64
// over 36 (kc,t) steps, barrier-free main loop, 3-deep A-register ring.
// 512 blocks x 4 waves; block tile 256o x 64px, wave tile 64o x 64px.
// LDS 39936B; __launch_bounds__(256,3) -> 3 blocks/CU (12 waves/CU).
// NOTE: bounds must leave >= ~152 unified VGPR+AGPR regs or the compiler
// spills the in-flight asm load ring -> garbage (round-12 lesson).
// ---------------------------------------------------------------------------
template <bool FUSE>
__global__ __launch_bounds__(256, 3) void tbn_conv_kernel(
    const float* __restrict__ src,        // quant source AND residual (NCHW)
    const signed char* __restrict__ Sr,   // [t*4+kc][256][64] i8
    const float* __restrict__ alpha,      // [256]
    float* __restrict__ out,              // [32][256][1024] f32
    const float* __restrict__ dpart, int nPart,  // delta partials
    const float* __restrict__ qg, const float* __restrict__ qb,
    const float* __restrict__ qm, const float* __restrict__ qv,   // own BN
    const float* __restrict__ fg, const float* __restrict__ fbt,
    const float* __restrict__ fm, const float* __restrict__ fv,   // next BN
    float* __restrict__ partials) {
    __shared__ __align__(16) char smem[39936];
    signed char* Bq = (signed char*)smem;            // 4*BQ_KC = 34816
    float* red  = (float*)smem;                      // aliases Bq[0:1024]
    float* sInv = (float*)(smem + 34816);
    float* sB   = (float*)(smem + 35840);
    float* sAl  = (float*)(smem + 36864);
    float* sInvS= (float*)(smem + 37888);
    float* sBS  = (float*)(smem + 38912);

    int bid = blockIdx.x;
    int wg = (bid & 7) * 64 + (bid >> 3);  // bijective, 512 % 8 == 0
    int n = wg >> 4;
    int pb = wg & 15;
    int tid = threadIdx.x, lane = tid & 63, wid = tid >> 6;
    int l15 = lane & 15, kg = lane >> 4;
    int y0 = pb * 2;   // first interior pixel-row of this 64-px tile

    // ---- prologue A: BN params + delta partial sums (red aliases Bq) ----
    {
        float inv = qg[tid] * rsqrtf(qv[tid] + BN_EPS);
        sInv[tid] = inv;
        sB[tid] = qb[tid] - qm[tid] * inv;
        sAl[tid] = alpha[tid];
        if (FUSE) {
            float finv = fg[tid] * rsqrtf(fv[tid] + BN_EPS);
            sInvS[tid] = finv;
            sBS[tid] = fbt[tid] - fm[tid] * finv;
        }
    }
    float s = 0.f;
    for (int i = tid; i < nPart; i += 256) s += dpart[i];
    red[tid] = s;
    __syncthreads();
    for (int off = 128; off > 0; off >>= 1) {
        if (tid < off) red[tid] += red[tid + off];
        __syncthreads();
    }
    float delta = red[0] * KSCALE;
    __syncthreads();   // everyone has read red[0]; Bq writes may begin

    // ---- prologue B: quantize 4x34x256 window into Bq ----
    // 512 pieces: quad = idx&7 (4-px group), cg = (idx>>3)&15, row = idx>>7
    const float4* src4 = (const float4*)src + (size_t)n * 65536;
#pragma unroll
    for (int k = 0; k < 2; ++k) {
        int idx = tid + 256 * k;
        int quad = idx & 7;
        int cg = (idx >> 3) & 15;
        int row = idx >> 7;          // 0..3 (padded window row)
        int absrow = y0 + row - 1;
        int wrd[4][4];
#pragma unroll
        for (int px = 0; px < 4; ++px)
#pragma unroll
            for (int d = 0; d < 4; ++d) wrd[px][d] = 0;
        if (absrow >= 0 && absrow < 32) {
#pragma unroll
            for (int j = 0; j < 16; ++j) {
                int c = cg * 16 + j;
                float4 v = src4[(size_t)c * 256 + absrow * 8 + quad];
                float inv = sInv[c], bb = sB[c];
                float va[4] = {v.x, v.y, v.z, v.w};
#pragma unroll
                for (int px = 0; px < 4; ++px) {
                    float t = va[px] * inv + bb;
                    int q = t > delta ? 1 : (t < -delta ? -1 : 0);
                    wrd[px][j >> 2] |= (q & 255) << (8 * (j & 3));
                }
            }
        }
        int kc = cg >> 2, kgp = cg & 3;
#pragma unroll
        for (int px = 0; px < 4; ++px) {
            int slot = quad * 4 + px + 1;
            int dst = kc * BQ_KC + row * 2176 + slot * 64 +
                      (((kgp + (slot >> 1)) & 3) << 4);
            int32x4 vv;
            vv[0] = wrd[px][0]; vv[1] = wrd[px][1];
            vv[2] = wrd[px][2]; vv[3] = wrd[px][3];
            *(int32x4*)(&Bq[dst]) = vv;
        }
    }
    // halo columns (slot 0 and 33): 128 zero pieces
    if (tid < 128) {
        int cg = tid & 15;
        int rest = tid >> 4;         // 0..7
        int row = rest >> 1, side = rest & 1;
        int slot = side ? 33 : 0;
        int kc = cg >> 2, kgp = cg & 3;
        int dst = kc * BQ_KC + row * 2176 + slot * 64 +
                  (((kgp + (slot >> 1)) & 3) << 4);
        int32x4 z; z[0] = 0; z[1] = 0; z[2] = 0; z[3] = 0;
        *(int32x4*)(&Bq[dst]) = z;
    }
    __syncthreads();   // Bq read-only hereafter (until epilogue barrier)

    // ---- main loop: barrier-free, 3-deep A ring only in vmcnt FIFO ----
    int o0 = wid * 64;
    const signed char* Abase = Sr + (size_t)(o0 + l15) * 64 + kg * 16;

    int32x4 acc[4][4];
#pragma unroll
    for (int m = 0; m < 4; ++m)
#pragma unroll
        for (int nn = 0; nn < 4; ++nn) {
            acc[m][nn][0] = 0; acc[m][nn][1] = 0;
            acc[m][nn][2] = 0; acc[m][nn][3] = 0;
        }

    int32x4 fa[3][4], fb[2][4];

#define GLD(D, P) \
    asm volatile("global_load_dwordx4 %0, %1, off" : "=v"(D) : "v"(P))
#define SLAB(I) ((((I) % 9) * 4) + ((I) / 9))
#define LOADA(I)                                                              \
    do {                                                                      \
        const signed char* pa_ = Abase + (size_t)SLAB(I) * SR_STEP;           \
        GLD(fa[(I) % 3][0], pa_);                                             \
        GLD(fa[(I) % 3][1], pa_ + 1024);                                      \
        GLD(fa[(I) % 3][2], pa_ + 2048);                                      \
        GLD(fa[(I) % 3][3], pa_ + 3072);                                      \
    } while (0)
#define LOADB(J, BUF)                                                         \
    do {                                                                      \
        const int kcj_ = (J) / 9, tj_ = (J) % 9;                              \
        const int kh_ = tj_ / 3 - 1, kw_ = tj_ % 3 - 1;                       \
        _Pragma("unroll")                                                     \
        for (int nn = 0; nn < 4; ++nn) {                                      \
            const int row_ = (nn >> 1) + 1 + kh_;                             \
            int slot_ = (nn & 1) * 16 + l15 + 1 + kw_;                        \
            int off_ = kcj_ * BQ_KC + row_ * 2176 + slot_ * 64 +              \
                       (((kg + (slot_ >> 1)) & 3) << 4);                      \
            fb[BUF][nn] = *(const int32x4*)(&Bq[off_]);                       \
        }                                                                     \
    } while (0)
#define MFMA16(I, BUF)                                                        \
    do {                                                                      \
        _Pragma("unroll")                                                     \
        for (int m = 0; m < 4; ++m)                                           \
            _Pragma("unroll")                                                 \
            for (int nn = 0; nn < 4; ++nn)                                    \
                acc[m][nn] = __builtin_amdgcn_mfma_i32_16x16x64_i8(           \
                    fa[(I) % 3][m], fb[BUF][nn], acc[m][nn], 0, 0, 0);        \
    } while (0)
#define WAITV(N)                                                              \
    do { asm volatile("s_waitcnt vmcnt(" #N ")" ::: "memory");                \
         __builtin_amdgcn_sched_barrier(0); } while (0)

    LOADA(0); LOADA(1); LOADA(2);
    LOADB(0, 0);
    // FIFO-exact: outstanding before wait at step i = A(i..min(i+2,35));
    // retire A(i): N=8 for i<=33, 4 at 34, 0 at 35.
#pragma unroll
    for (int i = 0; i < 36; ++i) {
        if (i <= 33)      WAITV(8);
        else if (i == 34) WAITV(4);
        else              WAITV(0);
        if (i < 35) LOADB(i + 1, (i + 1) & 1);
        MFMA16(i, i & 1);
        if (i + 3 <= 35) LOADA(i + 3);
    }
#undef GLD
#undef SLAB
#undef LOADA
#undef LOADB
#undef MFMA16
#undef WAITV

    // ---- epilogue: D col = l15 (pixel), row = kg*4 + r ----
    float psum = 0.f;
#pragma unroll
    for (int m = 0; m < 4; ++m) {
#pragma unroll
        for (int r = 0; r < 4; ++r) {
            int o = wid * 64 + m * 16 + kg * 4 + r;  // 0..255
            float al = sAl[o];
            float inv = 0.f, bb = 0.f;
            if (FUSE) { inv = sInvS[o]; bb = sBS[o]; }
            const float* rp = src + (size_t)n * 262144 + (size_t)o * 1024;
            float* op = out + (size_t)n * 262144 + (size_t)o * 1024;
#pragma unroll
            for (int nn = 0; nn < 4; ++nn) {
                int p = pb * 64 + nn * 16 + l15;
                float hv = rp[p] + al * (float)acc[m][nn][r];
                op[p] = hv;
                if (FUSE) psum += fabsf(hv * inv + bb);
            }
        }
    }
    if (FUSE) {
        __syncthreads();           // all waves done reading Bq (red aliases it)
        red[tid] = psum;
        __syncthreads();
        for (int off = 128; off > 0; off >>= 1) {
            if (tid < off) red[tid] += red[tid + off];
            __syncthreads();
        }
        if (tid == 0) partials[wg] = red[0];
    }
}

// ---------------------------------------------------------------------------
extern "C" void kernel_launch(void* const* d_in, const int* in_sizes, int n_in,
                              void* d_out, int out_size, void* d_ws, size_t ws_size,
                              hipStream_t stream) {
    (void)in_sizes; (void)n_in; (void)out_size; (void)ws_size;
    const float* x  = (const float*)d_in[0];
    const float* w1 = (const float*)d_in[1];
    const float* w2 = (const float*)d_in[2];
    const float* g1 = (const float*)d_in[3];
    const float* b1 = (const float*)d_in[4];
    const float* m1 = (const float*)d_in[5];
    const float* v1 = (const float*)d_in[6];
    const float* g2 = (const float*)d_in[7];
    const float* b2 = (const float*)d_in[8];
    const float* m2 = (const float*)d_in[9];
    const float* v2 = (const float*)d_in[10];
    float* out = (float*)d_out;
    char* ws = (char*)d_ws;

    float* red1   = (float*)(ws + 4096);       // 4096 floats
    float* redc   = (float*)(ws + 24576);      // 512 floats
    float* alpha1 = (float*)(ws + 28672);
    float* alpha2 = (float*)(ws + 29696);
    signed char* Sr1 = (signed char*)(ws + ((size_t)1 << 20));
    signed char* Sr2 = (signed char*)(ws + ((size_t)2 << 20));
    float* h         = (float*)(ws + ((size_t)4 << 20));   // 134 MB

    prep_w_kernel<<<512, 256, 0, stream>>>(w1, Sr1, alpha1, w2, Sr2, alpha2);
    bnabs_reduce_kernel<<<4096, 256, 0, stream>>>(x, g1, b1, m1, v1, red1);
    tbn_conv_kernel<true><<<512, 256, 0, stream>>>(
        x, Sr1, alpha1, h, red1, 4096,
        g1, b1, m1, v1, g2, b2, m2, v2, redc);
    tbn_conv_kernel<false><<<512, 256, 0, stream>>>(
        h, Sr2, alpha2, out, redc, 512,
        g2, b2, m2, v2, g2, b2, m2, v2, redc);
}

// Round 15
// 79.962 us; speedup vs baseline: 1.1597x; 1.0562x over previous
//
#include <hip/hip_runtime.h>

#define BN_EPS 1e-5f
#define SR_STEP  16384      // per (t,kc): 256 o * 64B
#define BQ_KC    8704       // 4 rows * 34 slots * 64B per kc
#define KSCALE   (0.7f / 8388608.0f)

typedef __attribute__((ext_vector_type(4))) int int32x4;

// ---------------------------------------------------------------------------
// Front-end (ONE launch, grid 2560):
//   blocks 0..511   : weight prep (set = bid>>8, o = bid&255)
//   blocks 512..2559: bnabs reduce over x (2048 partials)
// prep is tiny and rides under the BW-bound reduce.
// ---------------------------------------------------------------------------
__global__ void frontend_kernel(const float* __restrict__ w1,
                                signed char* __restrict__ Sr1,
                                float* __restrict__ alpha1,
                                const float* __restrict__ w2,
                                signed char* __restrict__ Sr2,
                                float* __restrict__ alpha2,
                                const float* __restrict__ x,
                                const float* __restrict__ gamma,
                                const float* __restrict__ beta,
                                const float* __restrict__ mean,
                                const float* __restrict__ var,
                                float* __restrict__ partials) {
    __shared__ __align__(16) signed char lsg[9][256];
    __shared__ float red[256];
    int bid = blockIdx.x;
    int tid = threadIdx.x;

    if (bid < 512) {
        // ---- weight prep ----
        int set = bid >> 8;
        const float* w = set ? w2 : w1;
        signed char* Sr = set ? Sr2 : Sr1;
        float* alpha = set ? alpha2 : alpha1;
        int o = bid & 255;
        const float* wp = w + (o * 256 + tid) * 9;
        float s = 0.f;
#pragma unroll
        for (int j = 0; j < 9; ++j) {
            float v = wp[j];
            s += fabsf(v);
            lsg[j][tid] = v > 0.f ? 1 : (v < 0.f ? -1 : 0);
        }
        red[tid] = s;
        __syncthreads();
        for (int off = 128; off > 0; off >>= 1) {
            if (tid < off) red[tid] += red[tid + off];
            __syncthreads();
        }
        if (tid == 0) alpha[o] = red[0] / 2304.0f;
        if (tid < 144) {
            int t = tid / 16, u = tid % 16;
            int c0 = u * 16;
            int kc = c0 >> 6, cb = c0 & 63;
            int32x4 v = *(const int32x4*)(&lsg[t][c0]);
            *(int32x4*)(Sr + (size_t)((t * 4 + kc) * 256 + o) * 64 + cb) = v;
        }
    } else {
        // ---- |bn1(x)| reduce: 2048 blocks x 256 thr x 4 float4 ----
        // i = rid*256 + tid + k*524288  covers [0, 2097152) exactly.
        int rid = bid - 512;
        const float4* x4 = (const float4*)x;
        float s = 0.f;
        int base = rid * 256 + tid;    // float4 index in [0, 524288)
#pragma unroll
        for (int k = 0; k < 4; ++k) {
            int i = base + k * 524288;
            int c = (i >> 8) & 255;
            float inv = gamma[c] * rsqrtf(var[c] + BN_EPS);
            float b = beta[c] - mean[c] * inv;
            float4 v = x4[i];
            s += fabsf(v.x * inv + b) + fabsf(v.y * inv + b) +
                 fabsf(v.z * inv + b) + fabsf(v.w * inv + b);
        }
        red[tid] = s;
        __syncthreads();
        for (int off = 128; off > 0; off >>= 1) {
            if (tid < off) red[tid] += red[tid + off];
            __syncthreads();
        }
        if (tid == 0) partials[rid] = red[0];
    }
}

// ---------------------------------------------------------------------------
// Fused TBN conv: in-block quantization into LDS, then i8 MFMA 16x16x64
// over 36 (kc,t) steps, barrier-free main loop, 3-deep A-register ring.
// 512 blocks x 4 waves; block tile 256o x 64px, wave tile 64o x 64px.
// LDS 39936B; __launch_bounds__(256,3) -> 3 blocks/CU capacity.
// NOTE: bounds must leave >= ~152 unified VGPR+AGPR regs or the compiler
// spills the in-flight asm load ring -> garbage (round-12 lesson).
// ---------------------------------------------------------------------------
template <bool FUSE>
__global__ __launch_bounds__(256, 3) void tbn_conv_kernel(
    const float* __restrict__ src,        // quant source AND residual (NCHW)
    const signed char* __restrict__ Sr,   // [t*4+kc][256][64] i8
    const float* __restrict__ alpha,      // [256]
    float* __restrict__ out,              // [32][256][1024] f32
    const float* __restrict__ dpart, int nPart,  // delta partials
    const float* __restrict__ qg, const float* __restrict__ qb,
    const float* __restrict__ qm, const float* __restrict__ qv,   // own BN
    const float* __restrict__ fg, const float* __restrict__ fbt,
    const float* __restrict__ fm, const float* __restrict__ fv,   // next BN
    float* __restrict__ partials) {
    __shared__ __align__(16) char smem[39936];
    signed char* Bq = (signed char*)smem;            // 4*BQ_KC = 34816
    float* red  = (float*)smem;                      // aliases Bq[0:1024]
    float* sInv = (float*)(smem + 34816);
    float* sB   = (float*)(smem + 35840);
    float* sAl  = (float*)(smem + 36864);
    float* sInvS= (float*)(smem + 37888);
    float* sBS  = (float*)(smem + 38912);

    int bid = blockIdx.x;
    int wg = (bid & 7) * 64 + (bid >> 3);  // bijective, 512 % 8 == 0
    int n = wg >> 4;
    int pb = wg & 15;
    int tid = threadIdx.x, lane = tid & 63, wid = tid >> 6;
    int l15 = lane & 15, kg = lane >> 4;
    int y0 = pb * 2;   // first interior pixel-row of this 64-px tile

    // ---- prologue A: BN params + delta partial sums (red aliases Bq) ----
    {
        float inv = qg[tid] * rsqrtf(qv[tid] + BN_EPS);
        sInv[tid] = inv;
        sB[tid] = qb[tid] - qm[tid] * inv;
        sAl[tid] = alpha[tid];
        if (FUSE) {
            float finv = fg[tid] * rsqrtf(fv[tid] + BN_EPS);
            sInvS[tid] = finv;
            sBS[tid] = fbt[tid] - fm[tid] * finv;
        }
    }
    float s = 0.f;
    for (int i = tid; i < nPart; i += 256) s += dpart[i];
    red[tid] = s;
    __syncthreads();
    for (int off = 128; off > 0; off >>= 1) {
        if (tid < off) red[tid] += red[tid + off];
        __syncthreads();
    }
    float delta = red[0] * KSCALE;
    __syncthreads();   // everyone has read red[0]; Bq writes may begin

    // ---- prologue B: quantize 4x34x256 window into Bq ----
    // 512 pieces: quad = idx&7 (4-px group), cg = (idx>>3)&15, row = idx>>7
    const float4* src4 = (const float4*)src + (size_t)n * 65536;
#pragma unroll
    for (int k = 0; k < 2; ++k) {
        int idx = tid + 256 * k;
        int quad = idx & 7;
        int cg = (idx >> 3) & 15;
        int row = idx >> 7;          // 0..3 (padded window row)
        int absrow = y0 + row - 1;
        int wrd[4][4];
#pragma unroll
        for (int px = 0; px < 4; ++px)
#pragma unroll
            for (int d = 0; d < 4; ++d) wrd[px][d] = 0;
        if (absrow >= 0 && absrow < 32) {
#pragma unroll
            for (int j = 0; j < 16; ++j) {
                int c = cg * 16 + j;
                float4 v = src4[(size_t)c * 256 + absrow * 8 + quad];
                float inv = sInv[c], bb = sB[c];
                float va[4] = {v.x, v.y, v.z, v.w};
#pragma unroll
                for (int px = 0; px < 4; ++px) {
                    float t = va[px] * inv + bb;
                    int q = t > delta ? 1 : (t < -delta ? -1 : 0);
                    wrd[px][j >> 2] |= (q & 255) << (8 * (j & 3));
                }
            }
        }
        int kc = cg >> 2, kgp = cg & 3;
#pragma unroll
        for (int px = 0; px < 4; ++px) {
            int slot = quad * 4 + px + 1;
            int dst = kc * BQ_KC + row * 2176 + slot * 64 +
                      (((kgp + (slot >> 1)) & 3) << 4);
            int32x4 vv;
            vv[0] = wrd[px][0]; vv[1] = wrd[px][1];
            vv[2] = wrd[px][2]; vv[3] = wrd[px][3];
            *(int32x4*)(&Bq[dst]) = vv;
        }
    }
    // halo columns (slot 0 and 33): 128 zero pieces
    if (tid < 128) {
        int cg = tid & 15;
        int rest = tid >> 4;         // 0..7
        int row = rest >> 1, side = rest & 1;
        int slot = side ? 33 : 0;
        int kc = cg >> 2, kgp = cg & 3;
        int dst = kc * BQ_KC + row * 2176 + slot * 64 +
                  (((kgp + (slot >> 1)) & 3) << 4);
        int32x4 z; z[0] = 0; z[1] = 0; z[2] = 0; z[3] = 0;
        *(int32x4*)(&Bq[dst]) = z;
    }
    __syncthreads();   // Bq read-only hereafter (until epilogue barrier)

    // ---- main loop: barrier-free, 3-deep A ring only in vmcnt FIFO ----
    int o0 = wid * 64;
    const signed char* Abase = Sr + (size_t)(o0 + l15) * 64 + kg * 16;

    int32x4 acc[4][4];
#pragma unroll
    for (int m = 0; m < 4; ++m)
#pragma unroll
        for (int nn = 0; nn < 4; ++nn) {
            acc[m][nn][0] = 0; acc[m][nn][1] = 0;
            acc[m][nn][2] = 0; acc[m][nn][3] = 0;
        }

    int32x4 fa[3][4], fb[2][4];

#define GLD(D, P) \
    asm volatile("global_load_dwordx4 %0, %1, off" : "=v"(D) : "v"(P))
#define SLAB(I) ((((I) % 9) * 4) + ((I) / 9))
#define LOADA(I)                                                              \
    do {                                                                      \
        const signed char* pa_ = Abase + (size_t)SLAB(I) * SR_STEP;           \
        GLD(fa[(I) % 3][0], pa_);                                             \
        GLD(fa[(I) % 3][1], pa_ + 1024);                                      \
        GLD(fa[(I) % 3][2], pa_ + 2048);                                      \
        GLD(fa[(I) % 3][3], pa_ + 3072);                                      \
    } while (0)
#define LOADB(J, BUF)                                                         \
    do {                                                                      \
        const int kcj_ = (J) / 9, tj_ = (J) % 9;                              \
        const int kh_ = tj_ / 3 - 1, kw_ = tj_ % 3 - 1;                       \
        _Pragma("unroll")                                                     \
        for (int nn = 0; nn < 4; ++nn) {                                      \
            const int row_ = (nn >> 1) + 1 + kh_;                             \
            int slot_ = (nn & 1) * 16 + l15 + 1 + kw_;                        \
            int off_ = kcj_ * BQ_KC + row_ * 2176 + slot_ * 64 +              \
                       (((kg + (slot_ >> 1)) & 3) << 4);                      \
            fb[BUF][nn] = *(const int32x4*)(&Bq[off_]);                       \
        }                                                                     \
    } while (0)
#define MFMA16(I, BUF)                                                        \
    do {                                                                      \
        _Pragma("unroll")                                                     \
        for (int m = 0; m < 4; ++m)                                           \
            _Pragma("unroll")                                                 \
            for (int nn = 0; nn < 4; ++nn)                                    \
                acc[m][nn] = __builtin_amdgcn_mfma_i32_16x16x64_i8(           \
                    fa[(I) % 3][m], fb[BUF][nn], acc[m][nn], 0, 0, 0);        \
    } while (0)
#define WAITV(N)                                                              \
    do { asm volatile("s_waitcnt vmcnt(" #N ")" ::: "memory");                \
         __builtin_amdgcn_sched_barrier(0); } while (0)

    LOADA(0); LOADA(1); LOADA(2);
    LOADB(0, 0);
    // FIFO-exact: outstanding before wait at step i = A(i..min(i+2,35));
    // retire A(i): N=8 for i<=33, 4 at 34, 0 at 35.
#pragma unroll
    for (int i = 0; i < 36; ++i) {
        if (i <= 33)      WAITV(8);
        else if (i == 34) WAITV(4);
        else              WAITV(0);
        if (i < 35) LOADB(i + 1, (i + 1) & 1);
        MFMA16(i, i & 1);
        if (i + 3 <= 35) LOADA(i + 3);
    }
#undef GLD
#undef SLAB
#undef LOADA
#undef LOADB
#undef MFMA16
#undef WAITV

    // ---- epilogue: D col = l15 (pixel), row = kg*4 + r ----
    float psum = 0.f;
#pragma unroll
    for (int m = 0; m < 4; ++m) {
#pragma unroll
        for (int r = 0; r < 4; ++r) {
            int o = wid * 64 + m * 16 + kg * 4 + r;  // 0..255
            float al = sAl[o];
            float inv = 0.f, bb = 0.f;
            if (FUSE) { inv = sInvS[o]; bb = sBS[o]; }
            const float* rp = src + (size_t)n * 262144 + (size_t)o * 1024;
            float* op = out + (size_t)n * 262144 + (size_t)o * 1024;
#pragma unroll
            for (int nn = 0; nn < 4; ++nn) {
                int p = pb * 64 + nn * 16 + l15;
                float hv = rp[p] + al * (float)acc[m][nn][r];
                op[p] = hv;
                if (FUSE) psum += fabsf(hv * inv + bb);
            }
        }
    }
    if (FUSE) {
        __syncthreads();           // all waves done reading Bq (red aliases it)
        red[tid] = psum;
        __syncthreads();
        for (int off = 128; off > 0; off >>= 1) {
            if (tid < off) red[tid] += red[tid + off];
            __syncthreads();
        }
        if (tid == 0) partials[wg] = red[0];
    }
}

// ---------------------------------------------------------------------------
extern "C" void kernel_launch(void* const* d_in, const int* in_sizes, int n_in,
                              void* d_out, int out_size, void* d_ws, size_t ws_size,
                              hipStream_t stream) {
    (void)in_sizes; (void)n_in; (void)out_size; (void)ws_size;
    const float* x  = (const float*)d_in[0];
    const float* w1 = (const float*)d_in[1];
    const float* w2 = (const float*)d_in[2];
    const float* g1 = (const float*)d_in[3];
    const float* b1 = (const float*)d_in[4];
    const float* m1 = (const float*)d_in[5];
    const float* v1 = (const float*)d_in[6];
    const float* g2 = (const float*)d_in[7];
    const float* b2 = (const float*)d_in[8];
    const float* m2 = (const float*)d_in[9];
    const float* v2 = (const float*)d_in[10];
    float* out = (float*)d_out;
    char* ws = (char*)d_ws;

    float* red1   = (float*)(ws + 4096);       // 2048 floats
    float* redc   = (float*)(ws + 16384);      // 512 floats
    float* alpha1 = (float*)(ws + 28672);
    float* alpha2 = (float*)(ws + 29696);
    signed char* Sr1 = (signed char*)(ws + ((size_t)1 << 20));
    signed char* Sr2 = (signed char*)(ws + ((size_t)2 << 20));
    float* h         = (float*)(ws + ((size_t)4 << 20));   // 134 MB

    frontend_kernel<<<2560, 256, 0, stream>>>(w1, Sr1, alpha1, w2, Sr2, alpha2,
                                              x, g1, b1, m1, v1, red1);
    tbn_conv_kernel<true><<<512, 256, 0, stream>>>(
        x, Sr1, alpha1, h, red1, 2048,
        g1, b1, m1, v1, g2, b2, m2, v2, redc);
    tbn_conv_kernel<false><<<512, 256, 0, stream>>>(
        h, Sr2, alpha2, out, redc, 512,
        g2, b2, m2, v2, g2, b2, m2, v2, redc);
}

// Round 17
// 69.668 us; speedup vs baseline: 1.3310x; 1.1478x over previous
//
#include <hip/hip_runtime.h>

#define BN_EPS 1e-5f
#define SR_STEP  16384      // per (t,kc): 256 o * 64B
#define BQ_KC    13056      // 6 rows * 34 slots * 64B per kc
#define KSCALE   (0.7f / 8388608.0f)

typedef __attribute__((ext_vector_type(4))) int int32x4;

// ---------------------------------------------------------------------------
// Front-end (ONE launch, grid 2560):
//   blocks 0..511   : weight prep (set = bid>>8, o = bid&255)
//   blocks 512..2559: bnabs reduce over x (2048 partials)
// ---------------------------------------------------------------------------
__global__ void frontend_kernel(const float* __restrict__ w1,
                                signed char* __restrict__ Sr1,
                                float* __restrict__ alpha1,
                                const float* __restrict__ w2,
                                signed char* __restrict__ Sr2,
                                float* __restrict__ alpha2,
                                const float* __restrict__ x,
                                const float* __restrict__ gamma,
                                const float* __restrict__ beta,
                                const float* __restrict__ mean,
                                const float* __restrict__ var,
                                float* __restrict__ partials) {
    __shared__ __align__(16) signed char lsg[9][256];
    __shared__ float red[256];
    int bid = blockIdx.x;
    int tid = threadIdx.x;

    if (bid < 512) {
        int set = bid >> 8;
        const float* w = set ? w2 : w1;
        signed char* Sr = set ? Sr2 : Sr1;
        float* alpha = set ? alpha2 : alpha1;
        int o = bid & 255;
        const float* wp = w + (o * 256 + tid) * 9;
        float s = 0.f;
#pragma unroll
        for (int j = 0; j < 9; ++j) {
            float v = wp[j];
            s += fabsf(v);
            lsg[j][tid] = v > 0.f ? 1 : (v < 0.f ? -1 : 0);
        }
        red[tid] = s;
        __syncthreads();
        for (int off = 128; off > 0; off >>= 1) {
            if (tid < off) red[tid] += red[tid + off];
            __syncthreads();
        }
        if (tid == 0) alpha[o] = red[0] / 2304.0f;
        if (tid < 144) {
            int t = tid / 16, u = tid % 16;
            int c0 = u * 16;
            int kc = c0 >> 6, cb = c0 & 63;
            int32x4 v = *(const int32x4*)(&lsg[t][c0]);
            *(int32x4*)(Sr + (size_t)((t * 4 + kc) * 256 + o) * 64 + cb) = v;
        }
    } else {
        // i = rid*256 + tid + k*524288 covers [0, 2097152) exactly.
        int rid = bid - 512;
        const float4* x4 = (const float4*)x;
        float s = 0.f;
        int base = rid * 256 + tid;
#pragma unroll
        for (int k = 0; k < 4; ++k) {
            int i = base + k * 524288;
            int c = (i >> 8) & 255;
            float inv = gamma[c] * rsqrtf(var[c] + BN_EPS);
            float b = beta[c] - mean[c] * inv;
            float4 v = x4[i];
            s += fabsf(v.x * inv + b) + fabsf(v.y * inv + b) +
                 fabsf(v.z * inv + b) + fabsf(v.w * inv + b);
        }
        red[tid] = s;
        __syncthreads();
        for (int off = 128; off > 0; off >>= 1) {
            if (tid < off) red[tid] += red[tid + off];
            __syncthreads();
        }
        if (tid == 0) partials[rid] = red[0];
    }
}

// ---------------------------------------------------------------------------
// Fused TBN conv: in-block quantization into LDS (6-row window), then i8
// MFMA 16x16x64 over 36 steps, barrier-free main loop, 3-deep A asm ring.
// 512 blocks (32n x 2ob x 8pb) x 4 waves; block 128o x 128px,
// wave 32o x 128px -> A-traffic per conv halves vs 64o x 64px tiling.
// LDS ~55.8KB -> 2 blocks/CU. __launch_bounds__(256,2): ~190 regs needed,
// bound gives 256 (r12 lesson: bound must exceed asm-ring register need).
// ---------------------------------------------------------------------------
template <bool FUSE>
__global__ __launch_bounds__(256, 2) void tbn_conv_kernel(
    const float* __restrict__ src,        // quant source AND residual (NCHW)
    const signed char* __restrict__ Sr,   // [t*4+kc][256][64] i8
    const float* __restrict__ alpha,      // [256]
    float* __restrict__ out,              // [32][256][1024] f32
    const float* __restrict__ dpart, int nPart,
    const float* __restrict__ qg, const float* __restrict__ qb,
    const float* __restrict__ qm, const float* __restrict__ qv,
    const float* __restrict__ fg, const float* __restrict__ fbt,
    const float* __restrict__ fm, const float* __restrict__ fv,
    float* __restrict__ partials) {
    __shared__ __align__(16) char smem[55808];
    signed char* Bq = (signed char*)smem;            // 4*BQ_KC = 52224
    float* red  = (float*)smem;                      // aliases Bq[0:1024]
    float* sInv = (float*)(smem + 52224);
    float* sB   = (float*)(smem + 53248);
    float* sAl  = (float*)(smem + 54272);            // 128
    float* sInvS= (float*)(smem + 54784);            // 128
    float* sBS  = (float*)(smem + 55296);            // 128

    int bid = blockIdx.x;
    int wg = (bid & 7) * 64 + (bid >> 3);  // bijective, 512 % 8 == 0
    int n = wg >> 4;
    int ob = (wg >> 3) & 1;
    int pb = wg & 7;
    int tid = threadIdx.x, lane = tid & 63, wid = tid >> 6;
    int l15 = lane & 15, kg = lane >> 4;
    int y0 = pb * 4;   // first interior pixel-row of this 128-px tile

    // ---- prologue A: BN params + delta partial sums (red aliases Bq) ----
    {
        float inv = qg[tid] * rsqrtf(qv[tid] + BN_EPS);
        sInv[tid] = inv;
        sB[tid] = qb[tid] - qm[tid] * inv;
    }
    if (tid < 128) {
        int o = ob * 128 + tid;
        sAl[tid] = alpha[o];
        if (FUSE) {
            float finv = fg[o] * rsqrtf(fv[o] + BN_EPS);
            sInvS[tid] = finv;
            sBS[tid] = fbt[o] - fm[o] * finv;
        }
    }
    float s = 0.f;
    for (int i = tid; i < nPart; i += 256) s += dpart[i];
    red[tid] = s;
    __syncthreads();
    for (int off = 128; off > 0; off >>= 1) {
        if (tid < off) red[tid] += red[tid + off];
        __syncthreads();
    }
    float delta = red[0] * KSCALE;
    __syncthreads();   // everyone has read red[0]; Bq writes may begin

    // ---- prologue B: quantize 6x34x256 window into Bq (r10 pattern) ----
    const float4* src4 = (const float4*)src + (size_t)n * 65536;
#pragma unroll
    for (int k = 0; k < 3; ++k) {
        int idx = tid + 256 * k;
        int quad = idx & 7;
        int cg2 = (idx >> 3) & 15;
        int row = idx >> 7;          // 0..5 (padded window row)
        int absrow = y0 + row - 1;
        int wrd[4][4];
#pragma unroll
        for (int px = 0; px < 4; ++px)
#pragma unroll
            for (int d = 0; d < 4; ++d) wrd[px][d] = 0;
        if (absrow >= 0 && absrow < 32) {
#pragma unroll
            for (int j = 0; j < 16; ++j) {
                int c = cg2 * 16 + j;
                float4 v = src4[(size_t)c * 256 + absrow * 8 + quad];
                float inv = sInv[c], bb = sB[c];
                float va[4] = {v.x, v.y, v.z, v.w};
#pragma unroll
                for (int px = 0; px < 4; ++px) {
                    float t = va[px] * inv + bb;
                    int q = t > delta ? 1 : (t < -delta ? -1 : 0);
                    wrd[px][j >> 2] |= (q & 255) << (8 * (j & 3));
                }
            }
        }
        int kc = cg2 >> 2, kgp = cg2 & 3;
#pragma unroll
        for (int px = 0; px < 4; ++px) {
            int slot = quad * 4 + px + 1;
            int dst = kc * BQ_KC + row * 2176 + slot * 64 +
                      (((kgp + (slot >> 1)) & 3) << 4);
            int32x4 vv;
            vv[0] = wrd[px][0]; vv[1] = wrd[px][1];
            vv[2] = wrd[px][2]; vv[3] = wrd[px][3];
            *(int32x4*)(&Bq[dst]) = vv;
        }
    }
    // halo columns (slot 0 and 33): 192 zero pieces
    if (tid < 192) {
        int cg2 = tid & 15;
        int rest = tid >> 4;         // 0..11
        int row = rest >> 1, side = rest & 1;
        int slot = side ? 33 : 0;
        int kc = cg2 >> 2, kgp = cg2 & 3;
        int dst = kc * BQ_KC + row * 2176 + slot * 64 +
                  (((kgp + (slot >> 1)) & 3) << 4);
        int32x4 z; z[0] = 0; z[1] = 0; z[2] = 0; z[3] = 0;
        *(int32x4*)(&Bq[dst]) = z;
    }
    __syncthreads();   // Bq read-only hereafter

    // ---- main loop: barrier-free, 3-deep A ring (2 loads/step) ----
    int o0 = ob * 128 + wid * 32;
    const signed char* Abase = Sr + (size_t)(o0 + l15) * 64 + kg * 16;

    int32x4 acc[2][8];
#pragma unroll
    for (int m = 0; m < 2; ++m)
#pragma unroll
        for (int nn = 0; nn < 8; ++nn) {
            acc[m][nn][0] = 0; acc[m][nn][1] = 0;
            acc[m][nn][2] = 0; acc[m][nn][3] = 0;
        }

    int32x4 fa[3][2], fb[2][8];

#define GLD(D, P) \
    asm volatile("global_load_dwordx4 %0, %1, off" : "=v"(D) : "v"(P))
#define SLAB(I) ((((I) % 9) * 4) + ((I) / 9))
#define LOADA(I)                                                              \
    do {                                                                      \
        const signed char* pa_ = Abase + (size_t)SLAB(I) * SR_STEP;           \
        GLD(fa[(I) % 3][0], pa_);                                             \
        GLD(fa[(I) % 3][1], pa_ + 1024);                                      \
    } while (0)
#define LOADB(J, BUF)                                                         \
    do {                                                                      \
        const int kcj_ = (J) / 9, tj_ = (J) % 9;                              \
        const int kh_ = tj_ / 3 - 1, kw_ = tj_ % 3 - 1;                       \
        _Pragma("unroll")                                                     \
        for (int nn = 0; nn < 8; ++nn) {                                      \
            const int row_ = (nn >> 1) + 1 + kh_;                             \
            int slot_ = (nn & 1) * 16 + l15 + 1 + kw_;                        \
            int off_ = kcj_ * BQ_KC + row_ * 2176 + slot_ * 64 +              \
                       (((kg + (slot_ >> 1)) & 3) << 4);                      \
            fb[BUF][nn] = *(const int32x4*)(&Bq[off_]);                       \
        }                                                                     \
    } while (0)
#define MFMA16(I, BUF)                                                        \
    do {                                                                      \
        _Pragma("unroll")                                                     \
        for (int m = 0; m < 2; ++m)                                           \
            _Pragma("unroll")                                                 \
            for (int nn = 0; nn < 8; ++nn)                                    \
                acc[m][nn] = __builtin_amdgcn_mfma_i32_16x16x64_i8(           \
                    fa[(I) % 3][m], fb[BUF][nn], acc[m][nn], 0, 0, 0);        \
    } while (0)
#define WAITV(N)                                                              \
    do { asm volatile("s_waitcnt vmcnt(" #N ")" ::: "memory");                \
         __builtin_amdgcn_sched_barrier(0); } while (0)

    LOADA(0); LOADA(1); LOADA(2);
    LOADB(0, 0);
    // FIFO-exact (2 loads per LOADA): before wait at step i the FIFO holds
    // A(i),A(i+1),A(i+2) = 6; retire A(i): N=4 for i<=33, 2 at 34, 0 at 35.
#pragma unroll
    for (int i = 0; i < 36; ++i) {
        if (i <= 33)      WAITV(4);
        else if (i == 34) WAITV(2);
        else              WAITV(0);
        if (i < 35) LOADB(i + 1, (i + 1) & 1);
        MFMA16(i, i & 1);
        if (i + 3 <= 35) LOADA(i + 3);
    }
#undef GLD
#undef SLAB
#undef LOADA
#undef LOADB
#undef MFMA16
#undef WAITV

    // ---- epilogue: D col = l15 (pixel), row = kg*4 + r ----
    float psum = 0.f;
#pragma unroll
    for (int m = 0; m < 2; ++m) {
#pragma unroll
        for (int r = 0; r < 4; ++r) {
            int oLoc = wid * 32 + m * 16 + kg * 4 + r;  // 0..127
            int o = ob * 128 + oLoc;
            float al = sAl[oLoc];
            float inv = 0.f, bb = 0.f;
            if (FUSE) { inv = sInvS[oLoc]; bb = sBS[oLoc]; }
            const float* rp = src + (size_t)n * 262144 + (size_t)o * 1024;
            float* op = out + (size_t)n * 262144 + (size_t)o * 1024;
#pragma unroll
            for (int nn = 0; nn < 8; ++nn) {
                int p = pb * 128 + nn * 16 + l15;
                float hv = rp[p] + al * (float)acc[m][nn][r];
                op[p] = hv;
                if (FUSE) psum += fabsf(hv * inv + bb);
            }
        }
    }
    if (FUSE) {
        __syncthreads();           // all waves done reading Bq (red aliases it)
        red[tid] = psum;
        __syncthreads();
        for (int off = 128; off > 0; off >>= 1) {
            if (tid < off) red[tid] += red[tid + off];
            __syncthreads();
        }
        if (tid == 0) partials[wg] = red[0];
    }
}

// ---------------------------------------------------------------------------
extern "C" void kernel_launch(void* const* d_in, const int* in_sizes, int n_in,
                              void* d_out, int out_size, void* d_ws, size_t ws_size,
                              hipStream_t stream) {
    (void)in_sizes; (void)n_in; (void)out_size; (void)ws_size;
    const float* x  = (const float*)d_in[0];
    const float* w1 = (const float*)d_in[1];
    const float* w2 = (const float*)d_in[2];
    const float* g1 = (const float*)d_in[3];
    const float* b1 = (const float*)d_in[4];
    const float* m1 = (const float*)d_in[5];
    const float* v1 = (const float*)d_in[6];
    const float* g2 = (const float*)d_in[7];
    const float* b2 = (const float*)d_in[8];
    const float* m2 = (const float*)d_in[9];
    const float* v2 = (const float*)d_in[10];
    float* out = (float*)d_out;
    char* ws = (char*)d_ws;

    float* red1   = (float*)(ws + 4096);       // 2048 floats
    float* redc   = (float*)(ws + 16384);      // 512 floats
    float* alpha1 = (float*)(ws + 28672);
    float* alpha2 = (float*)(ws + 29696);
    signed char* Sr1 = (signed char*)(ws + ((size_t)1 << 20));
    signed char* Sr2 = (signed char*)(ws + ((size_t)2 << 20));
    float* h         = (float*)(ws + ((size_t)4 << 20));   // 134 MB

    frontend_kernel<<<2560, 256, 0, stream>>>(w1, Sr1, alpha1, w2, Sr2, alpha2,
                                              x, g1, b1, m1, v1, red1);
    tbn_conv_kernel<true><<<512, 256, 0, stream>>>(
        x, Sr1, alpha1, h, red1, 2048,
        g1, b1, m1, v1, g2, b2, m2, v2, redc);
    tbn_conv_kernel<false><<<512, 256, 0, stream>>>(
        h, Sr2, alpha2, out, redc, 512,
        g2, b2, m2, v2, g2, b2, m2, v2, redc);
}

// Round 18
// 67.284 us; speedup vs baseline: 1.3782x; 1.0354x over previous
//
#include <hip/hip_runtime.h>

#define BN_EPS 1e-5f
#define SR_STEP  16384      // per (t,kc): 256 o * 64B
#define BQ_KC    13056      // 6 rows * 34 slots * 64B per kc
#define KSCALE   (0.7f / 8388608.0f)

typedef __attribute__((ext_vector_type(4))) int int32x4;

// ---------------------------------------------------------------------------
// Front-end (ONE launch, grid 2560):
//   blocks 0..511   : weight prep (set = bid>>8, o = bid&255)
//   blocks 512..2559: bnabs reduce over x (2048 partials)
// ---------------------------------------------------------------------------
__global__ void frontend_kernel(const float* __restrict__ w1,
                                signed char* __restrict__ Sr1,
                                float* __restrict__ alpha1,
                                const float* __restrict__ w2,
                                signed char* __restrict__ Sr2,
                                float* __restrict__ alpha2,
                                const float* __restrict__ x,
                                const float* __restrict__ gamma,
                                const float* __restrict__ beta,
                                const float* __restrict__ mean,
                                const float* __restrict__ var,
                                float* __restrict__ partials) {
    __shared__ __align__(16) signed char lsg[9][256];
    __shared__ float red[256];
    int bid = blockIdx.x;
    int tid = threadIdx.x;

    if (bid < 512) {
        int set = bid >> 8;
        const float* w = set ? w2 : w1;
        signed char* Sr = set ? Sr2 : Sr1;
        float* alpha = set ? alpha2 : alpha1;
        int o = bid & 255;
        const float* wp = w + (o * 256 + tid) * 9;
        float s = 0.f;
#pragma unroll
        for (int j = 0; j < 9; ++j) {
            float v = wp[j];
            s += fabsf(v);
            lsg[j][tid] = v > 0.f ? 1 : (v < 0.f ? -1 : 0);
        }
        red[tid] = s;
        __syncthreads();
        for (int off = 128; off > 0; off >>= 1) {
            if (tid < off) red[tid] += red[tid + off];
            __syncthreads();
        }
        if (tid == 0) alpha[o] = red[0] / 2304.0f;
        if (tid < 144) {
            int t = tid / 16, u = tid % 16;
            int c0 = u * 16;
            int kc = c0 >> 6, cb = c0 & 63;
            int32x4 v = *(const int32x4*)(&lsg[t][c0]);
            *(int32x4*)(Sr + (size_t)((t * 4 + kc) * 256 + o) * 64 + cb) = v;
        }
    } else {
        // i = rid*256 + tid + k*524288 covers [0, 2097152) exactly.
        int rid = bid - 512;
        const float4* x4 = (const float4*)x;
        float s = 0.f;
        int base = rid * 256 + tid;
#pragma unroll
        for (int k = 0; k < 4; ++k) {
            int i = base + k * 524288;
            int c = (i >> 8) & 255;
            float inv = gamma[c] * rsqrtf(var[c] + BN_EPS);
            float b = beta[c] - mean[c] * inv;
            float4 v = x4[i];
            s += fabsf(v.x * inv + b) + fabsf(v.y * inv + b) +
                 fabsf(v.z * inv + b) + fabsf(v.w * inv + b);
        }
        red[tid] = s;
        __syncthreads();
        for (int off = 128; off > 0; off >>= 1) {
            if (tid < off) red[tid] += red[tid + off];
            __syncthreads();
        }
        if (tid == 0) partials[rid] = red[0];
    }
}

// ---------------------------------------------------------------------------
// Fused TBN conv: in-block quantization into LDS (6-row window, done ONCE
// per (n,pb) window), then i8 MFMA 16x16x64 over 36 steps, barrier-free
// main loop, 3-deep A asm ring. Grid 256 (32n x 8pb) x 8 waves (512 thr);
// block tile 256o x 128px, wave tile 32o x 128px.
// LDS 57344B. __launch_bounds__(512,1): regalloc unconstrained (~190 regs
// needed; r12 lesson: never bound below the asm-ring register need).
// ---------------------------------------------------------------------------
template <bool FUSE>
__global__ __launch_bounds__(512, 1) void tbn_conv_kernel(
    const float* __restrict__ src,        // quant source AND residual (NCHW)
    const signed char* __restrict__ Sr,   // [t*4+kc][256][64] i8
    const float* __restrict__ alpha,      // [256]
    float* __restrict__ out,              // [32][256][1024] f32
    const float* __restrict__ dpart, int nPart,
    const float* __restrict__ qg, const float* __restrict__ qb,
    const float* __restrict__ qm, const float* __restrict__ qv,
    const float* __restrict__ fg, const float* __restrict__ fbt,
    const float* __restrict__ fm, const float* __restrict__ fv,
    float* __restrict__ partials) {
    __shared__ __align__(16) char smem[57344];
    signed char* Bq = (signed char*)smem;            // 4*BQ_KC = 52224
    float* red  = (float*)smem;                      // aliases Bq[0:2048]
    float* sInv = (float*)(smem + 52224);
    float* sB   = (float*)(smem + 53248);
    float* sAl  = (float*)(smem + 54272);
    float* sInvS= (float*)(smem + 55296);
    float* sBS  = (float*)(smem + 56320);

    int bid = blockIdx.x;
    int wg = (bid & 7) * 32 + (bid >> 3);  // bijective, 256 % 8 == 0
    int n = wg >> 3;
    int pb = wg & 7;
    int tid = threadIdx.x, lane = tid & 63, wid = tid >> 6;  // wid 0..7
    int l15 = lane & 15, kg = lane >> 4;
    int y0 = pb * 4;   // first interior pixel-row of this 128-px tile

    // ---- prologue A: BN params + delta partial sums (red aliases Bq) ----
    if (tid < 256) {
        float inv = qg[tid] * rsqrtf(qv[tid] + BN_EPS);
        sInv[tid] = inv;
        sB[tid] = qb[tid] - qm[tid] * inv;
        sAl[tid] = alpha[tid];
        if (FUSE) {
            float finv = fg[tid] * rsqrtf(fv[tid] + BN_EPS);
            sInvS[tid] = finv;
            sBS[tid] = fbt[tid] - fm[tid] * finv;
        }
    }
    float s = 0.f;
    for (int i = tid; i < nPart; i += 512) s += dpart[i];
    red[tid] = s;
    __syncthreads();
    for (int off = 256; off > 0; off >>= 1) {
        if (tid < off) red[tid] += red[tid + off];
        __syncthreads();
    }
    float delta = red[0] * KSCALE;
    __syncthreads();   // everyone has read red[0]; Bq writes may begin

    // ---- prologue B: quantize 6x34x256 window into Bq (768 pieces) ----
    const float4* src4 = (const float4*)src + (size_t)n * 65536;
#pragma unroll
    for (int k = 0; k < 2; ++k) {
        int idx = tid + 512 * k;
        if (idx < 768) {
            int quad = idx & 7;
            int cg2 = (idx >> 3) & 15;
            int row = idx >> 7;          // 0..5 (padded window row)
            int absrow = y0 + row - 1;
            int wrd[4][4];
#pragma unroll
            for (int px = 0; px < 4; ++px)
#pragma unroll
                for (int d = 0; d < 4; ++d) wrd[px][d] = 0;
            if (absrow >= 0 && absrow < 32) {
#pragma unroll
                for (int j = 0; j < 16; ++j) {
                    int c = cg2 * 16 + j;
                    float4 v = src4[(size_t)c * 256 + absrow * 8 + quad];
                    float inv = sInv[c], bb = sB[c];
                    float va[4] = {v.x, v.y, v.z, v.w};
#pragma unroll
                    for (int px = 0; px < 4; ++px) {
                        float t = va[px] * inv + bb;
                        int q = t > delta ? 1 : (t < -delta ? -1 : 0);
                        wrd[px][j >> 2] |= (q & 255) << (8 * (j & 3));
                    }
                }
            }
            int kc = cg2 >> 2, kgp = cg2 & 3;
#pragma unroll
            for (int px = 0; px < 4; ++px) {
                int slot = quad * 4 + px + 1;
                int dst = kc * BQ_KC + row * 2176 + slot * 64 +
                          (((kgp + (slot >> 1)) & 3) << 4);
                int32x4 vv;
                vv[0] = wrd[px][0]; vv[1] = wrd[px][1];
                vv[2] = wrd[px][2]; vv[3] = wrd[px][3];
                *(int32x4*)(&Bq[dst]) = vv;
            }
        }
    }
    // halo columns (slot 0 and 33): 192 zero pieces
    if (tid < 192) {
        int cg2 = tid & 15;
        int rest = tid >> 4;         // 0..11
        int row = rest >> 1, side = rest & 1;
        int slot = side ? 33 : 0;
        int kc = cg2 >> 2, kgp = cg2 & 3;
        int dst = kc * BQ_KC + row * 2176 + slot * 64 +
                  (((kgp + (slot >> 1)) & 3) << 4);
        int32x4 z; z[0] = 0; z[1] = 0; z[2] = 0; z[3] = 0;
        *(int32x4*)(&Bq[dst]) = z;
    }
    __syncthreads();   // Bq read-only hereafter

    // ---- main loop: barrier-free, 3-deep A ring (2 loads/step) ----
    int o0 = wid * 32;
    const signed char* Abase = Sr + (size_t)(o0 + l15) * 64 + kg * 16;

    int32x4 acc[2][8];
#pragma unroll
    for (int m = 0; m < 2; ++m)
#pragma unroll
        for (int nn = 0; nn < 8; ++nn) {
            acc[m][nn][0] = 0; acc[m][nn][1] = 0;
            acc[m][nn][2] = 0; acc[m][nn][3] = 0;
        }

    int32x4 fa[3][2], fb[2][8];

#define GLD(D, P) \
    asm volatile("global_load_dwordx4 %0, %1, off" : "=v"(D) : "v"(P))
#define SLAB(I) ((((I) % 9) * 4) + ((I) / 9))
#define LOADA(I)                                                              \
    do {                                                                      \
        const signed char* pa_ = Abase + (size_t)SLAB(I) * SR_STEP;           \
        GLD(fa[(I) % 3][0], pa_);                                             \
        GLD(fa[(I) % 3][1], pa_ + 1024);                                      \
    } while (0)
#define LOADB(J, BUF)                                                         \
    do {                                                                      \
        const int kcj_ = (J) / 9, tj_ = (J) % 9;                              \
        const int kh_ = tj_ / 3 - 1, kw_ = tj_ % 3 - 1;                       \
        _Pragma("unroll")                                                     \
        for (int nn = 0; nn < 8; ++nn) {                                      \
            const int row_ = (nn >> 1) + 1 + kh_;                             \
            int slot_ = (nn & 1) * 16 + l15 + 1 + kw_;                        \
            int off_ = kcj_ * BQ_KC + row_ * 2176 + slot_ * 64 +              \
                       (((kg + (slot_ >> 1)) & 3) << 4);                      \
            fb[BUF][nn] = *(const int32x4*)(&Bq[off_]);                       \
        }                                                                     \
    } while (0)
#define MFMA16(I, BUF)                                                        \
    do {                                                                      \
        _Pragma("unroll")                                                     \
        for (int m = 0; m < 2; ++m)                                           \
            _Pragma("unroll")                                                 \
            for (int nn = 0; nn < 8; ++nn)                                    \
                acc[m][nn] = __builtin_amdgcn_mfma_i32_16x16x64_i8(           \
                    fa[(I) % 3][m], fb[BUF][nn], acc[m][nn], 0, 0, 0);        \
    } while (0)
#define WAITV(N)                                                              \
    do { asm volatile("s_waitcnt vmcnt(" #N ")" ::: "memory");                \
         __builtin_amdgcn_sched_barrier(0); } while (0)

    LOADA(0); LOADA(1); LOADA(2);
    LOADB(0, 0);
    // FIFO-exact (2 loads per LOADA): before wait at step i the FIFO holds
    // A(i),A(i+1),A(i+2) = 6; retire A(i): N=4 for i<=33, 2 at 34, 0 at 35.
#pragma unroll
    for (int i = 0; i < 36; ++i) {
        if (i <= 33)      WAITV(4);
        else if (i == 34) WAITV(2);
        else              WAITV(0);
        if (i < 35) LOADB(i + 1, (i + 1) & 1);
        MFMA16(i, i & 1);
        if (i + 3 <= 35) LOADA(i + 3);
    }
#undef GLD
#undef SLAB
#undef LOADA
#undef LOADB
#undef MFMA16
#undef WAITV

    // ---- epilogue: D col = l15 (pixel), row = kg*4 + r ----
    float psum = 0.f;
#pragma unroll
    for (int m = 0; m < 2; ++m) {
#pragma unroll
        for (int r = 0; r < 4; ++r) {
            int o = wid * 32 + m * 16 + kg * 4 + r;  // 0..255
            float al = sAl[o];
            float inv = 0.f, bb = 0.f;
            if (FUSE) { inv = sInvS[o]; bb = sBS[o]; }
            const float* rp = src + (size_t)n * 262144 + (size_t)o * 1024;
            float* op = out + (size_t)n * 262144 + (size_t)o * 1024;
#pragma unroll
            for (int nn = 0; nn < 8; ++nn) {
                int p = pb * 128 + nn * 16 + l15;
                float hv = rp[p] + al * (float)acc[m][nn][r];
                op[p] = hv;
                if (FUSE) psum += fabsf(hv * inv + bb);
            }
        }
    }
    if (FUSE) {
        __syncthreads();           // all waves done reading Bq (red aliases it)
        red[tid] = psum;
        __syncthreads();
        for (int off = 256; off > 0; off >>= 1) {
            if (tid < off) red[tid] += red[tid + off];
            __syncthreads();
        }
        if (tid == 0) partials[wg] = red[0];
    }
}

// ---------------------------------------------------------------------------
extern "C" void kernel_launch(void* const* d_in, const int* in_sizes, int n_in,
                              void* d_out, int out_size, void* d_ws, size_t ws_size,
                              hipStream_t stream) {
    (void)in_sizes; (void)n_in; (void)out_size; (void)ws_size;
    const float* x  = (const float*)d_in[0];
    const float* w1 = (const float*)d_in[1];
    const float* w2 = (const float*)d_in[2];
    const float* g1 = (const float*)d_in[3];
    const float* b1 = (const float*)d_in[4];
    const float* m1 = (const float*)d_in[5];
    const float* v1 = (const float*)d_in[6];
    const float* g2 = (const float*)d_in[7];
    const float* b2 = (const float*)d_in[8];
    const float* m2 = (const float*)d_in[9];
    const float* v2 = (const float*)d_in[10];
    float* out = (float*)d_out;
    char* ws = (char*)d_ws;

    float* red1   = (float*)(ws + 4096);       // 2048 floats
    float* redc   = (float*)(ws + 16384);      // 256 floats
    float* alpha1 = (float*)(ws + 28672);
    float* alpha2 = (float*)(ws + 29696);
    signed char* Sr1 = (signed char*)(ws + ((size_t)1 << 20));
    signed char* Sr2 = (signed char*)(ws + ((size_t)2 << 20));
    float* h         = (float*)(ws + ((size_t)4 << 20));   // 134 MB

    frontend_kernel<<<2560, 256, 0, stream>>>(w1, Sr1, alpha1, w2, Sr2, alpha2,
                                              x, g1, b1, m1, v1, red1);
    tbn_conv_kernel<true><<<256, 512, 0, stream>>>(
        x, Sr1, alpha1, h, red1, 2048,
        g1, b1, m1, v1, g2, b2, m2, v2, redc);
    tbn_conv_kernel<false><<<256, 512, 0, stream>>>(
        h, Sr2, alpha2, out, redc, 256,
        g2, b2, m2, v2, g2, b2, m2, v2, redc);
}